// Round 10
// baseline (170.393 us; speedup 1.0000x reference)
//
#include <hip/hip_runtime.h>
#include <cstdint>

#define BLOCK_SIZE 256
#define NPOS 63          // 9*7 spatial positions per batch
#define NB   3           // batches per wave (triple-batch ILP)
#define BPB  12          // batches per block = 4 waves x 3 batches/wave

typedef __attribute__((ext_vector_type(8))) _Float16 f16x8;     // 8 f16, 4 VGPRs
typedef __attribute__((ext_vector_type(4))) float f32x4;
typedef __attribute__((ext_vector_type(4))) unsigned int uint4v;

// f32 -> f16 RNE bits (low 16) — v_cvt_f16_f32 (default RNE)
__device__ __forceinline__ unsigned rne_f16(float a) {
    _Float16 h = (_Float16)a;
    return (unsigned)__builtin_bit_cast(unsigned short, h);
}
// pack two f32 -> 2 f16 RTZ in ONE v_cvt_pkrtz_f16_f32 (short0=a, short1=b)
__device__ __forceinline__ unsigned pack_f16(float a, float b) {
    auto t = __builtin_amdgcn_cvt_pkrtz(a, b);
    return __builtin_bit_cast(unsigned, t);
}

// R23 -> R24: WIDTH 3, WEIGHTS SPLIT BY CRITICALITY. R23 (all weights in
// LDS, 32 b128 reads/i-tile on the h1 critical path) fit at 80 VGPR but
// RAISED total VALU work 19% -> 89.6 us. R19 (width 2, all-register
// weights) = 68.3 us best. Recombination:
//  - W1/b1 in REGISTERS (R19): h1 build stays pure-VALU, no lgkm waits.
//  - W3/b2 in LDS (R20-proven broadcast, conflict-free): epilogue-only,
//    consumed AFTER the MFMA cluster -> off critical path. Saves 64
//    invariant VGPRs vs pure-register width 3.
//  - width 3: nominal peak ~120 VGPR; R17 proved the RA grants 124.
// Tripwire: VGPR=100 + WRITE>20MB/LDS>12KB = RA refused -> revert to R19.
// Per-batch arithmetic bit-identical to R19 (f16 single-product MFMA).
__global__ __launch_bounds__(BLOCK_SIZE) void carnet_fused(
    const float* __restrict__ x,      // (B, 9, 7) flat
    const int*   __restrict__ adj,    // (B, 45)
    const float* __restrict__ ctx,    // (B, 45)
    const float* __restrict__ gcn_W,  // (7, 7)
    const float* __restrict__ gcn_b,  // (7)
    const float* __restrict__ ctx_W,  // (45, 63)
    const float* __restrict__ ctx_b,  // (63)
    const float* __restrict__ W1,     // (64, 2)
    const float* __restrict__ b1,     // (64)
    const float* __restrict__ W2,     // (64, 64)
    const float* __restrict__ b2,     // (64)
    const float* __restrict__ W3,     // (2, 64)
    const float* __restrict__ b3,     // (2)
    float* __restrict__ out,          // (B, 2, 9, 7) flat
    const int nbatch)
{
    __shared__ short sh2b[64 * 64];   // 8192 B, XOR-swizzled, RNE f16 of W2
    __shared__ float w3b2[192];       // [0..127] = W3 (2x64), [128..191] = b2

    const int t    = threadIdx.x;
    const int lane = t & 63;

    // ---- staging: W2 fp32 -> RNE f16 plane, swizzled LDS write ----
    {
        const int r  = t >> 2;
        const int cq = t & 3;
        const float* wsrc = W2 + r * 64 + cq * 16;
        const float4 w0 = ((const float4*)wsrc)[0];
        const float4 w1 = ((const float4*)wsrc)[1];
        const float4 w2v = ((const float4*)wsrc)[2];
        const float4 w3v = ((const float4*)wsrc)[3];
        uint4v hA = { rne_f16(w0.x)  | (rne_f16(w0.y)  << 16),
                      rne_f16(w0.z)  | (rne_f16(w0.w)  << 16),
                      rne_f16(w1.x)  | (rne_f16(w1.y)  << 16),
                      rne_f16(w1.z)  | (rne_f16(w1.w)  << 16) };
        uint4v hB = { rne_f16(w2v.x) | (rne_f16(w2v.y) << 16),
                      rne_f16(w2v.z) | (rne_f16(w2v.w) << 16),
                      rne_f16(w3v.x) | (rne_f16(w3v.y) << 16),
                      rne_f16(w3v.z) | (rne_f16(w3v.w) << 16) };
        const int sA = ((2 * cq)     ^ (r & 7)) * 8;
        const int sB = ((2 * cq + 1) ^ (r & 7)) * 8;
        *(uint4v*)&sh2b[r * 64 + sA] = hA;
        *(uint4v*)&sh2b[r * 64 + sB] = hB;
        if (t < 192) w3b2[t] = (t < 128) ? W3[t] : b2[t - 128];
    }

    // ---- three wave-uniform batches per wave ----
    const int bbase = blockIdx.x * BPB + (t >> 6);
    int  bs[NB];
    bool vld[NB];
#pragma unroll
    for (int u = 0; u < NB; ++u) {
        const int braw = bbase + u * 4;
        vld[u] = (braw < nbatch);
        bs[u]  = __builtin_amdgcn_readfirstlane(vld[u] ? braw : (nbatch - 1));
    }

    const int p = lane < 63 ? lane : 62;
    const int n = p / 7;
    const int f = p - n * 7;
    const int snn = 9 * n - (n * (n - 1)) / 2 - n;

    // ========== PHASE 1 (triple, interleaved chains) ==========
    uint64_t am[NB];
#pragma unroll
    for (int u = 0; u < NB; ++u) {
        int av = 0;
        if (lane < 45) av = adj[bs[u] * 45 + lane];
        am[u] = __ballot(av != 0);
    }

    float d[NB][9];
#pragma unroll
    for (int i = 0; i < 9; ++i) {
        const int s = 9 * i - (i * (i - 1)) / 2;
        const uint64_t mk = (1ull << (8 - i)) - 1ull;
#pragma unroll
        for (int u = 0; u < NB; ++u)
            d[u][i] = __frsqrt_rn((float)(1 + __popcll((am[u] >> (s + 1)) & mk)));
    }

    float yv[NB] = {0.f, 0.f, 0.f};
#pragma unroll
    for (int k = 0; k < 7; ++k) {
        const float g = gcn_W[k * 7 + f];            // shared across batches
#pragma unroll
        for (int u = 0; u < NB; ++u)
            yv[u] = fmaf(x[bs[u] * 63 + n * 7 + k], g, yv[u]);
    }

    // z dot: one acc per batch (3 interleaved chains supply the ILP)
    float zt[NB] = {0.f, 0.f, 0.f};
#pragma unroll
    for (int m = 0; m < 9; ++m) {
        int sh = snn + m;
        sh = sh < 0 ? 0 : sh;
        const bool up = (m > n);
#pragma unroll
        for (int u = 0; u < NB; ++u) {
            const float ym = __shfl(yv[u], m * 7 + f);
            const float tm = ((m == n) || (up && ((am[u] >> sh) & 1ull))) ? d[u][m] : 0.f;
            zt[u] = fmaf(tm, ym, zt[u]);
        }
    }
    const float gbf = gcn_b[f];
    float zv[NB];
#pragma unroll
    for (int u = 0; u < NB; ++u) zv[u] = fmaf(d[u][n], zt[u], gbf);

    // ctx dots: weight column loads shared across batches; 2 accs/batch
    const float cbias = ctx_b[p];
    float c0[NB] = {cbias, cbias, cbias};
    float c1[NB] = {0.f, 0.f, 0.f};
#pragma unroll
    for (int q = 0; q < 44; q += 2) {
        const float w0 = ctx_W[q * 63 + p];
        const float w1 = ctx_W[(q + 1) * 63 + p];
#pragma unroll
        for (int u = 0; u < NB; ++u) {
            c0[u] = fmaf(ctx[bs[u] * 45 + q],     w0, c0[u]);
            c1[u] = fmaf(ctx[bs[u] * 45 + q + 1], w1, c1[u]);
        }
    }
    const float w44 = ctx_W[44 * 63 + p];
    float cvv[NB];
#pragma unroll
    for (int u = 0; u < NB; ++u) {
        c0[u] = fmaf(ctx[bs[u] * 45 + 44], w44, c0[u]);
        cvv[u] = fmaxf(c0[u] + c1[u], 0.f);
    }

    // ========== PHASE 2: MFMA (operand-swapped, f16, triple-batch) =======
    const int cl   = lane & 15;       // position within i-tile (B-operand n)
    const int quad = lane >> 4;       // k-octet / C row group (channel)
    const int s0 = (quad ^ (cl & 7)) * 16;

    // h1-stage weights in REGISTERS (latency-critical, R19-proven)
    float2 wp0[8], wp1[8];
    float  bb0[8], bb1[8];
#pragma unroll
    for (int j = 0; j < 8; ++j) {
        const int o = quad * 8 + j;
        wp0[j] = *(const float2*)(W1 + 2 * o);
        bb0[j] = b1[o];
        wp1[j] = *(const float2*)(W1 + 2 * (o + 32));
        bb1[j] = b1[o + 32];
    }
    const float b30 = b3[0], b31 = b3[1];

    float* __restrict__ ob[NB];
#pragma unroll
    for (int u = 0; u < NB; ++u) ob[u] = out + bs[u] * 126;

    const char* sh2bB_ = (const char*)sh2b;

    __syncthreads();   // staging complete before first LDS read

#pragma unroll 1
    for (int i = 0; i < 4; ++i) {
        float zm[NB], cm[NB];
#pragma unroll
        for (int u = 0; u < NB; ++u) {
            zm[u] = __shfl(zv[u],  i * 16 + cl);
            cm[u] = __shfl(cvv[u], i * 16 + cl);
        }

        // h1 fragments for all three batches (independent chains, pure VALU)
        f16x8 ah0[NB], ah1[NB];
#pragma unroll
        for (int u = 0; u < NB; ++u) {
            uint4v p0, p1;
#pragma unroll
            for (int jj = 0; jj < 4; ++jj) {
                float ha = fmaxf(fmaf(wp0[2*jj].x,   zm[u], fmaf(wp0[2*jj].y,   cm[u], bb0[2*jj])),   0.f);
                float hb = fmaxf(fmaf(wp0[2*jj+1].x, zm[u], fmaf(wp0[2*jj+1].y, cm[u], bb0[2*jj+1])), 0.f);
                p0[jj] = pack_f16(ha, hb);
                ha = fmaxf(fmaf(wp1[2*jj].x,   zm[u], fmaf(wp1[2*jj].y,   cm[u], bb1[2*jj])),   0.f);
                hb = fmaxf(fmaf(wp1[2*jj+1].x, zm[u], fmaf(wp1[2*jj+1].y, cm[u], bb1[2*jj+1])), 0.f);
                p1[jj] = pack_f16(ha, hb);
            }
            ah0[u] = __builtin_bit_cast(f16x8, p0);
            ah1[u] = __builtin_bit_cast(f16x8, p1);
        }

        // b2 quads from LDS (anti-LICM ties: transient, off critical path)
        f32x4 acc[NB][4];
#pragma unroll
        for (int k2 = 0; k2 < 4; ++k2) {
            int o = 128 + k2 * 16 + quad * 4;
            asm volatile("" : "+v"(o));
            const f32x4 bq = *(const f32x4*)&w3b2[o];
#pragma unroll
            for (int u = 0; u < NB; ++u) acc[u][k2] = bq;
        }

        // A = W2 f16 frag (LDS): 2 ds_read_b128 feed SIX MFMAs (3 batches)
#pragma unroll
        for (int nt = 0; nt < 4; ++nt) {
            int bo = cl * 128 + s0;
            asm volatile("" : "+v"(bo));
            const int bo2 = (cl * 128) | (s0 ^ 64);
            const f16x8 wf0 = *(const f16x8*)(sh2bB_ + bo  + nt * 2048);
            const f16x8 wf1 = *(const f16x8*)(sh2bB_ + bo2 + nt * 2048);
#pragma unroll
            for (int u = 0; u < NB; ++u) {
                acc[u][nt] = __builtin_amdgcn_mfma_f32_16x16x32_f16(wf0, ah0[u], acc[u][nt], 0, 0, 0);
                acc[u][nt] = __builtin_amdgcn_mfma_f32_16x16x32_f16(wf1, ah1[u], acc[u][nt], 0, 0, 0);
            }
        }

        // W3 rows from LDS (anti-LICM ties, broadcast, epilogue-only)
        f32x4 wa_[4], wb_[4];
#pragma unroll
        for (int k2 = 0; k2 < 4; ++k2) {
            int o = k2 * 16 + quad * 4;
            asm volatile("" : "+v"(o));
            wa_[k2] = *(const f32x4*)&w3b2[o];
            wb_[k2] = *(const f32x4*)&w3b2[64 + o];
        }

        // Epilogue (channel-major): relu + W3 dot, quad-reduce, store
        const int pp = i * 16 + cl;
#pragma unroll
        for (int u = 0; u < NB; ++u) {
            float q0 = 0.f, q1 = 0.f;
#pragma unroll
            for (int k2 = 0; k2 < 4; ++k2) {
#pragma unroll
                for (int e = 0; e < 4; ++e) {
                    const float h = fmaxf(acc[u][k2][e], 0.f);
                    q0 = fmaf(h, wa_[k2][e], q0);
                    q1 = fmaf(h, wb_[k2][e], q1);
                }
            }
            q0 += __shfl_xor(q0, 16); q0 += __shfl_xor(q0, 32);
            q1 += __shfl_xor(q1, 16); q1 += __shfl_xor(q1, 32);
            if (quad == 0 && pp < NPOS && vld[u]) {
                ob[u][pp]        = q0 + b30;
                ob[u][NPOS + pp] = q1 + b31;
            }
        }
    }
}

extern "C" void kernel_launch(void* const* d_in, const int* in_sizes, int n_in,
                              void* d_out, int out_size, void* d_ws, size_t ws_size,
                              hipStream_t stream) {
    const float* x     = (const float*)d_in[0];
    const int*   adj   = (const int*)  d_in[1];
    const float* ctx   = (const float*)d_in[2];
    const float* gcn_W = (const float*)d_in[3];
    const float* gcn_b = (const float*)d_in[4];
    const float* ctx_W = (const float*)d_in[5];
    const float* ctx_b = (const float*)d_in[6];
    const float* W1    = (const float*)d_in[7];
    const float* b1    = (const float*)d_in[8];
    const float* W2    = (const float*)d_in[9];
    const float* b2    = (const float*)d_in[10];
    const float* W3    = (const float*)d_in[11];
    const float* b3    = (const float*)d_in[12];
    float* out = (float*)d_out;

    const int nbatch = in_sizes[1] / 45;            // B = 32768
    const int grid = (nbatch + BPB - 1) / BPB;      // 12 batches per block
    carnet_fused<<<grid, BLOCK_SIZE, 0, stream>>>(
        x, adj, ctx, gcn_W, gcn_b, ctx_W, ctx_b,
        W1, b1, W2, b2, W3, b3, out, nbatch);
}

// Round 11
// 159.974 us; speedup vs baseline: 1.0651x; 1.0651x over previous
//
#include <hip/hip_runtime.h>
#include <cstdint>

#define BLOCK_SIZE 256
#define NPOS 63          // 9*7 spatial positions per batch
#define BPB  8           // batches per block = 4 waves x 2 batches/wave

typedef __attribute__((ext_vector_type(8))) _Float16 f16x8;     // 8 f16, 4 VGPRs
typedef __attribute__((ext_vector_type(4))) float f32x4;
typedef __attribute__((ext_vector_type(2))) float f32x2;
typedef __attribute__((ext_vector_type(4))) unsigned int uint4v;

// f32 -> f16 RNE bits (low 16) — v_cvt_f16_f32 (default RNE)
__device__ __forceinline__ unsigned rne_f16(float a) {
    _Float16 h = (_Float16)a;
    return (unsigned)__builtin_bit_cast(unsigned short, h);
}
// pack two f32 -> 2 f16 RTZ in ONE v_cvt_pkrtz_f16_f32 (short0=a, short1=b)
__device__ __forceinline__ unsigned pack_f16(float a, float b) {
    auto t = __builtin_amdgcn_cvt_pkrtz(a, b);
    return __builtin_bit_cast(unsigned, t);
}
// packed f32 fma/max -> v_pk_fma_f32 / v_pk_max_f32 (VOP3P, 2 f32/issue)
__device__ __forceinline__ f32x2 pk_fma(f32x2 a, f32x2 b, f32x2 c) {
    return __builtin_elementwise_fma(a, b, c);
}
__device__ __forceinline__ f32x2 pk_relu(f32x2 a) {
    return __builtin_elementwise_max(a, (f32x2){0.f, 0.f});
}

// R24 -> R25: BACK TO R19 BASE + VOP3P PACKED MATH. Width experiments
// settled: width 2 / all-register weights (R19, 68.3 us) beats width 3
// (91 us: LDS weight re-reads add VALU+lgkm on critical path, occupancy
// drops) and width 4 (RA refuses ~190 regs: spills 3 ways, VGPR pinned
// 100). R19's VALU integral 44.4 us-units (~830 instr/batch) is the
// floor at 100% busy — so cut the instruction count:
//  - h1 build: pairs via v_pk_fma_f32/v_pk_max_f32 (14 -> 8 issues/jj),
//    BIT-IDENTICAL (pk_fma = two IEEE f32 fmas).
//  - epilogue: channel-pair packing (48 -> ~26 issues/i-tile/batch),
//    reassociation +-ulp only.
//  ~ -170 VALU/batch (-20%) on an unchanged schedule; regs unchanged.
// Tripwire: dur unchanged => compiler scalarized -> inline-asm VOP3P next.
__global__ __launch_bounds__(BLOCK_SIZE) void carnet_fused(
    const float* __restrict__ x,      // (B, 9, 7) flat
    const int*   __restrict__ adj,    // (B, 45)
    const float* __restrict__ ctx,    // (B, 45)
    const float* __restrict__ gcn_W,  // (7, 7)
    const float* __restrict__ gcn_b,  // (7)
    const float* __restrict__ ctx_W,  // (45, 63)
    const float* __restrict__ ctx_b,  // (63)
    const float* __restrict__ W1,     // (64, 2)
    const float* __restrict__ b1,     // (64)
    const float* __restrict__ W2,     // (64, 64)
    const float* __restrict__ b2,     // (64)
    const float* __restrict__ W3,     // (2, 64)
    const float* __restrict__ b3,     // (2)
    float* __restrict__ out,          // (B, 2, 9, 7) flat
    const int nbatch)
{
    __shared__ short sh2b[64 * 64];   // 8192 B, XOR-swizzled, RNE f16 of W2

    const int t    = threadIdx.x;
    const int lane = t & 63;

    // ---- staging: W2 fp32 -> RNE f16 plane, swizzled LDS write ----
    {
        const int r  = t >> 2;
        const int cq = t & 3;
        const float* wsrc = W2 + r * 64 + cq * 16;
        const float4 w0 = ((const float4*)wsrc)[0];
        const float4 w1 = ((const float4*)wsrc)[1];
        const float4 w2v = ((const float4*)wsrc)[2];
        const float4 w3v = ((const float4*)wsrc)[3];
        uint4v hA = { rne_f16(w0.x)  | (rne_f16(w0.y)  << 16),
                      rne_f16(w0.z)  | (rne_f16(w0.w)  << 16),
                      rne_f16(w1.x)  | (rne_f16(w1.y)  << 16),
                      rne_f16(w1.z)  | (rne_f16(w1.w)  << 16) };
        uint4v hB = { rne_f16(w2v.x) | (rne_f16(w2v.y) << 16),
                      rne_f16(w2v.z) | (rne_f16(w2v.w) << 16),
                      rne_f16(w3v.x) | (rne_f16(w3v.y) << 16),
                      rne_f16(w3v.z) | (rne_f16(w3v.w) << 16) };
        const int sA = ((2 * cq)     ^ (r & 7)) * 8;
        const int sB = ((2 * cq + 1) ^ (r & 7)) * 8;
        *(uint4v*)&sh2b[r * 64 + sA] = hA;
        *(uint4v*)&sh2b[r * 64 + sB] = hB;
    }

    // ---- two wave-uniform batches per wave ----
    const int bA = __builtin_amdgcn_readfirstlane(blockIdx.x * BPB + (t >> 6));
    const int bBr = bA + 4;                                    // batch B raw
    const bool hasB = (bBr < nbatch);
    const int bB = __builtin_amdgcn_readfirstlane(hasB ? bBr : bA);

    const int p = lane < 63 ? lane : 62;
    const int n = p / 7;
    const int f = p - n * 7;

    // ========== PHASE 1 (dual, interleaved chains) ==========
    const int* abA = adj + bA * 45;
    const int* abB = adj + bB * 45;
    int avA = 0, avB = 0;
    if (lane < 45) { avA = abA[lane]; avB = abB[lane]; }
    const uint64_t amA = __ballot(avA != 0);
    const uint64_t amB = __ballot(avB != 0);

    float dA[9], dB[9];
#pragma unroll
    for (int i = 0; i < 9; ++i) {
        const int s = 9 * i - (i * (i - 1)) / 2;
        const uint64_t mk = (1ull << (8 - i)) - 1ull;
        dA[i] = __frsqrt_rn((float)(1 + __popcll((amA >> (s + 1)) & mk)));
        dB[i] = __frsqrt_rn((float)(1 + __popcll((amB >> (s + 1)) & mk)));
    }

    const float* xbA = x + bA * 63;
    const float* xbB = x + bB * 63;
    float yA = 0.f, yB = 0.f;
#pragma unroll
    for (int k = 0; k < 7; ++k) {
        const float g = gcn_W[k * 7 + f];            // shared across pair
        yA = fmaf(xbA[n * 7 + k], g, yA);
        yB = fmaf(xbB[n * 7 + k], g, yB);
    }

    // z dot: 3 accumulators per batch, chains interleaved
    float zA0 = 0.f, zA1 = 0.f, zA2 = 0.f, zB0 = 0.f, zB1 = 0.f, zB2 = 0.f;
    const int snn = 9 * n - (n * (n - 1)) / 2 - n;
#pragma unroll
    for (int m = 0; m < 9; ++m) {
        const float ymA = __shfl(yA, m * 7 + f);
        const float ymB = __shfl(yB, m * 7 + f);
        int sh = snn + m;
        sh = sh < 0 ? 0 : sh;
        const bool up = (m > n);
        const float tA = ((m == n) || (up && ((amA >> sh) & 1ull))) ? dA[m] : 0.f;
        const float tB = ((m == n) || (up && ((amB >> sh) & 1ull))) ? dB[m] : 0.f;
        if (m < 3)      { zA0 = fmaf(tA, ymA, zA0); zB0 = fmaf(tB, ymB, zB0); }
        else if (m < 6) { zA1 = fmaf(tA, ymA, zA1); zB1 = fmaf(tB, ymB, zB1); }
        else            { zA2 = fmaf(tA, ymA, zA2); zB2 = fmaf(tB, ymB, zB2); }
    }
    const float gbf = gcn_b[f];
    const float zvA = fmaf(dA[n], (zA0 + zA1) + zA2, gbf);
    const float zvB = fmaf(dB[n], (zB0 + zB1) + zB2, gbf);

    // ctx dots: ctx_W column loads SHARED across the pair; cb* wave-uniform
    const float* cbA = ctx + bA * 45;
    const float* cbB = ctx + bB * 45;
    const float cb0 = ctx_b[p];
    float aA0 = cb0, aA1 = 0.f, aA2 = 0.f, aA3 = 0.f;
    float aB0 = cb0, aB1 = 0.f, aB2 = 0.f, aB3 = 0.f;
#pragma unroll
    for (int q = 0; q < 44; q += 4) {
        const float w0 = ctx_W[q * 63 + p];
        const float w1 = ctx_W[(q + 1) * 63 + p];
        const float w2 = ctx_W[(q + 2) * 63 + p];
        const float w3 = ctx_W[(q + 3) * 63 + p];
        aA0 = fmaf(cbA[q],     w0, aA0);  aB0 = fmaf(cbB[q],     w0, aB0);
        aA1 = fmaf(cbA[q + 1], w1, aA1);  aB1 = fmaf(cbB[q + 1], w1, aB1);
        aA2 = fmaf(cbA[q + 2], w2, aA2);  aB2 = fmaf(cbB[q + 2], w2, aB2);
        aA3 = fmaf(cbA[q + 3], w3, aA3);  aB3 = fmaf(cbB[q + 3], w3, aB3);
    }
    const float w44 = ctx_W[44 * 63 + p];
    aA0 = fmaf(cbA[44], w44, aA0);  aB0 = fmaf(cbB[44], w44, aB0);
    const float cvA = fmaxf((aA0 + aA1) + (aA2 + aA3), 0.f);
    const float cvB = fmaxf((aB0 + aB1) + (aB2 + aB3), 0.f);

    // ========== PHASE 2: MFMA (operand-swapped, f16, dual-batch) ==========
    const int cl   = lane & 15;       // position within i-tile (B-operand n)
    const int quad = lane >> 4;       // k-octet / C row group (channel)
    const int s0 = (quad ^ (cl & 7)) * 16;

    // h1-stage weights as CHANNEL-PAIR vectors (VOP3P operands).
    // w1z0[jj] = z-coeffs of channels (2jj, 2jj+1) of group quad*8 (+0/+32)
    f32x2 w1z0[4], w1c0[4], w1b0[4], w1z1[4], w1c1[4], w1b1[4];
#pragma unroll
    for (int jj = 0; jj < 4; ++jj) {
        const int o = quad * 8 + 2 * jj;
        const float2 pa = *(const float2*)(W1 + 2 * o);
        const float2 pb = *(const float2*)(W1 + 2 * (o + 1));
        w1z0[jj] = (f32x2){pa.x, pb.x};
        w1c0[jj] = (f32x2){pa.y, pb.y};
        w1b0[jj] = (f32x2){b1[o], b1[o + 1]};
        const float2 qa = *(const float2*)(W1 + 2 * (o + 32));
        const float2 qb = *(const float2*)(W1 + 2 * (o + 33));
        w1z1[jj] = (f32x2){qa.x, qb.x};
        w1c1[jj] = (f32x2){qa.y, qb.y};
        w1b1[jj] = (f32x2){b1[o + 32], b1[o + 33]};
    }

    const float4 b2q0 = *(const float4*)(b2 + quad * 4);
    const float4 b2q1 = *(const float4*)(b2 + 16 + quad * 4);
    const float4 b2q2 = *(const float4*)(b2 + 32 + quad * 4);
    const float4 b2q3 = *(const float4*)(b2 + 48 + quad * 4);
    const float4 wa0 = *(const float4*)(W3 + quad * 4);
    const float4 wa1 = *(const float4*)(W3 + 16 + quad * 4);
    const float4 wa2 = *(const float4*)(W3 + 32 + quad * 4);
    const float4 wa3 = *(const float4*)(W3 + 48 + quad * 4);
    const float4 wb0 = *(const float4*)(W3 + 64 + quad * 4);
    const float4 wb1 = *(const float4*)(W3 + 80 + quad * 4);
    const float4 wb2 = *(const float4*)(W3 + 96 + quad * 4);
    const float4 wb3 = *(const float4*)(W3 + 112 + quad * 4);
    const float b30 = b3[0], b31 = b3[1];
    float* __restrict__ obA = out + bA * 126;
    float* __restrict__ obB = out + bB * 126;

    const char* sh2bB_ = (const char*)sh2b;

    __syncthreads();   // staging complete before first B read

    // epilogue: packed relu + W3 dot (channel pairs), quad-reduce, store
    auto epilogue = [&](const f32x4& a0, const f32x4& a1,
                        const f32x4& a2, const f32x4& a3,
                        float* obp, int pp, bool valid) {
        f32x2 qa = {0.f, 0.f}, qb = {0.f, 0.f};
#define EPI(av, wav, wbv) {                                            \
        const f32x2 h01 = pk_relu((f32x2){av[0], av[1]});              \
        const f32x2 h23 = pk_relu((f32x2){av[2], av[3]});              \
        qa = pk_fma(h01, (f32x2){wav.x, wav.y}, qa);                   \
        qa = pk_fma(h23, (f32x2){wav.z, wav.w}, qa);                   \
        qb = pk_fma(h01, (f32x2){wbv.x, wbv.y}, qb);                   \
        qb = pk_fma(h23, (f32x2){wbv.z, wbv.w}, qb); }
        EPI(a0, wa0, wb0) EPI(a1, wa1, wb1) EPI(a2, wa2, wb2) EPI(a3, wa3, wb3)
#undef EPI
        float q0 = qa.x + qa.y, q1 = qb.x + qb.y;
        q0 += __shfl_xor(q0, 16); q0 += __shfl_xor(q0, 32);
        q1 += __shfl_xor(q1, 16); q1 += __shfl_xor(q1, 32);
        if (quad == 0 && pp < NPOS && valid) {
            obp[pp]        = q0 + b30;
            obp[NPOS + pp] = q1 + b31;
        }
    };

#pragma unroll 1
    for (int i = 0; i < 4; ++i) {
        const float zmA = __shfl(zvA, i * 16 + cl);
        const float cmA = __shfl(cvA, i * 16 + cl);
        const float zmB = __shfl(zvB, i * 16 + cl);
        const float cmB = __shfl(cvB, i * 16 + cl);
        const f32x2 zzA = {zmA, zmA}, ccA = {cmA, cmA};
        const f32x2 zzB = {zmB, zmB}, ccB = {cmB, cmB};

        // h1 fragments: packed fma/relu per channel pair (bit-identical
        // to scalar: v_pk_fma_f32 = two IEEE f32 fmas)
        uint4v pA0, pA1, pB0, pB1;
#pragma unroll
        for (int jj = 0; jj < 4; ++jj) {
            f32x2 h;
            h = pk_relu(pk_fma(w1z0[jj], zzA, pk_fma(w1c0[jj], ccA, w1b0[jj])));
            pA0[jj] = pack_f16(h.x, h.y);
            h = pk_relu(pk_fma(w1z1[jj], zzA, pk_fma(w1c1[jj], ccA, w1b1[jj])));
            pA1[jj] = pack_f16(h.x, h.y);
            h = pk_relu(pk_fma(w1z0[jj], zzB, pk_fma(w1c0[jj], ccB, w1b0[jj])));
            pB0[jj] = pack_f16(h.x, h.y);
            h = pk_relu(pk_fma(w1z1[jj], zzB, pk_fma(w1c1[jj], ccB, w1b1[jj])));
            pB1[jj] = pack_f16(h.x, h.y);
        }
        const f16x8 ahA0 = __builtin_bit_cast(f16x8, pA0);
        const f16x8 ahA1 = __builtin_bit_cast(f16x8, pA1);
        const f16x8 ahB0 = __builtin_bit_cast(f16x8, pB0);
        const f16x8 ahB1 = __builtin_bit_cast(f16x8, pB1);

        f32x4 accA0 = {b2q0.x, b2q0.y, b2q0.z, b2q0.w};
        f32x4 accA1 = {b2q1.x, b2q1.y, b2q1.z, b2q1.w};
        f32x4 accA2 = {b2q2.x, b2q2.y, b2q2.z, b2q2.w};
        f32x4 accA3 = {b2q3.x, b2q3.y, b2q3.z, b2q3.w};
        f32x4 accB0 = accA0, accB1 = accA1, accB2 = accA2, accB3 = accA3;

        // A-operand W2 LDS reads shared by BOTH batches: 2 ds_read_b128
        // feed 4 MFMAs per STEP (A/B interleaved = independent).
#define STEP(nt) {                                                                      \
        int bo = cl * 128 + s0;                                                         \
        asm volatile("" : "+v"(bo));                                                    \
        const int bo2 = (cl * 128) | (s0 ^ 64);                                         \
        const f16x8 wf0 = *(const f16x8*)(sh2bB_ + bo  + ((nt) * 2048));                \
        const f16x8 wf1 = *(const f16x8*)(sh2bB_ + bo2 + ((nt) * 2048));                \
        accA##nt = __builtin_amdgcn_mfma_f32_16x16x32_f16(wf0, ahA0, accA##nt, 0, 0, 0); \
        accB##nt = __builtin_amdgcn_mfma_f32_16x16x32_f16(wf0, ahB0, accB##nt, 0, 0, 0); \
        accA##nt = __builtin_amdgcn_mfma_f32_16x16x32_f16(wf1, ahA1, accA##nt, 0, 0, 0); \
        accB##nt = __builtin_amdgcn_mfma_f32_16x16x32_f16(wf1, ahB1, accB##nt, 0, 0, 0); }
        STEP(0) STEP(1) STEP(2) STEP(3)
#undef STEP

        const int pp = i * 16 + cl;
        epilogue(accA0, accA1, accA2, accA3, obA, pp, true);
        epilogue(accB0, accB1, accB2, accB3, obB, pp, hasB);
    }
}

extern "C" void kernel_launch(void* const* d_in, const int* in_sizes, int n_in,
                              void* d_out, int out_size, void* d_ws, size_t ws_size,
                              hipStream_t stream) {
    const float* x     = (const float*)d_in[0];
    const int*   adj   = (const int*)  d_in[1];
    const float* ctx   = (const float*)d_in[2];
    const float* gcn_W = (const float*)d_in[3];
    const float* gcn_b = (const float*)d_in[4];
    const float* ctx_W = (const float*)d_in[5];
    const float* ctx_b = (const float*)d_in[6];
    const float* W1    = (const float*)d_in[7];
    const float* b1    = (const float*)d_in[8];
    const float* W2    = (const float*)d_in[9];
    const float* b2    = (const float*)d_in[10];
    const float* W3    = (const float*)d_in[11];
    const float* b3    = (const float*)d_in[12];
    float* out = (float*)d_out;

    const int nbatch = in_sizes[1] / 45;            // B = 32768
    const int grid = (nbatch + BPB - 1) / BPB;      // 8 batches per block
    carnet_fused<<<grid, BLOCK_SIZE, 0, stream>>>(
        x, adj, ctx, gcn_W, gcn_b, ctx_W, ctx_b,
        W1, b1, W2, b2, W3, b3, out, nbatch);
}

// Round 12
// 151.409 us; speedup vs baseline: 1.1254x; 1.0566x over previous
//
#include <hip/hip_runtime.h>
#include <cstdint>

#define BLOCK_SIZE 256
#define NPOS 63          // 9*7 spatial positions per batch
#define BPB  8           // batches per block = 4 waves x 2 batches/wave

typedef __attribute__((ext_vector_type(8))) _Float16 f16x8;     // 8 f16, 4 VGPRs
typedef __attribute__((ext_vector_type(4))) float f32x4;
typedef __attribute__((ext_vector_type(4))) unsigned int uint4v;
typedef __attribute__((ext_vector_type(4))) int int4v;

// f32 -> f16 RNE bits (low 16) — v_cvt_f16_f32 (default RNE)
__device__ __forceinline__ unsigned rne_f16(float a) {
    _Float16 h = (_Float16)a;
    return (unsigned)__builtin_bit_cast(unsigned short, h);
}
// pack two f32 -> 2 f16 RTZ in ONE v_cvt_pkrtz_f16_f32 (short0=a, short1=b)
__device__ __forceinline__ unsigned pack_f16(float a, float b) {
    auto t = __builtin_amdgcn_cvt_pkrtz(a, b);
    return __builtin_bit_cast(unsigned, t);
}

// R25 -> R26: R19 BASE + BLOCK-COOPERATIVE INPUT STAGING. Evidence chain:
// widening past 2 fails (RA refuses ~190 regs; LDS-weight re-reads add
// critical-path work), VALU-cutting fails (R25: -11% VALU instr, dur
// WORSE -> not VALU-issue-bound). R19 (68.3 us) is stall-bound: ~16k of
// 22.8k wave-cycles are stalls, dominated by cold-stream input loads
// (adj/x/ctx, ~20 MB arrays, 300-900 cyc) hit serially at each wave's
// phase-1 with only ~2.2 waves/SIMD to hide them.
// Fix: the block's 8 batches need just 4.9 KB of inputs, CONTIGUOUS in
// global. Stage via 3 coalesced float4/int4 bursts into LDS behind the
// EXISTING barrier; phase-1 reads LDS (x 9-bank spread, ctx broadcast,
// adj 2-way=free). Cold latency collapses into one parallel burst/block.
// Everything else (math, schedule, geometry) byte-identical to R19;
// R25's packed math REVERTED (regressed).
__global__ __launch_bounds__(BLOCK_SIZE) void carnet_fused(
    const float* __restrict__ x,      // (B, 9, 7) flat
    const int*   __restrict__ adj,    // (B, 45)
    const float* __restrict__ ctx,    // (B, 45)
    const float* __restrict__ gcn_W,  // (7, 7)
    const float* __restrict__ gcn_b,  // (7)
    const float* __restrict__ ctx_W,  // (45, 63)
    const float* __restrict__ ctx_b,  // (63)
    const float* __restrict__ W1,     // (64, 2)
    const float* __restrict__ b1,     // (64)
    const float* __restrict__ W2,     // (64, 64)
    const float* __restrict__ b2,     // (64)
    const float* __restrict__ W3,     // (2, 64)
    const float* __restrict__ b3,     // (2)
    float* __restrict__ out,          // (B, 2, 9, 7) flat
    const int nbatch)
{
    __shared__ short sh2b[64 * 64];   // 8192 B, XOR-swizzled, RNE f16 of W2
    __shared__ float sh_x[BPB * 63];  // 2016 B, block's x rows
    __shared__ float sh_ctx[BPB * 45];// 1440 B, block's ctx rows
    __shared__ int   sh_adj[BPB * 45];// 1440 B, block's adj rows

    const int t    = threadIdx.x;
    const int lane = t & 63;
    const int base = blockIdx.x * BPB;

    // ---- staging: W2 fp32 -> RNE f16 plane, swizzled LDS write ----
    {
        const int r  = t >> 2;
        const int cq = t & 3;
        const float* wsrc = W2 + r * 64 + cq * 16;
        const float4 w0 = ((const float4*)wsrc)[0];
        const float4 w1 = ((const float4*)wsrc)[1];
        const float4 w2v = ((const float4*)wsrc)[2];
        const float4 w3v = ((const float4*)wsrc)[3];
        uint4v hA = { rne_f16(w0.x)  | (rne_f16(w0.y)  << 16),
                      rne_f16(w0.z)  | (rne_f16(w0.w)  << 16),
                      rne_f16(w1.x)  | (rne_f16(w1.y)  << 16),
                      rne_f16(w1.z)  | (rne_f16(w1.w)  << 16) };
        uint4v hB = { rne_f16(w2v.x) | (rne_f16(w2v.y) << 16),
                      rne_f16(w2v.z) | (rne_f16(w2v.w) << 16),
                      rne_f16(w3v.x) | (rne_f16(w3v.y) << 16),
                      rne_f16(w3v.z) | (rne_f16(w3v.w) << 16) };
        const int sA = ((2 * cq)     ^ (r & 7)) * 8;
        const int sB = ((2 * cq + 1) ^ (r & 7)) * 8;
        *(uint4v*)&sh2b[r * 64 + sA] = hA;
        *(uint4v*)&sh2b[r * 64 + sB] = hB;
    }

    // ---- staging: block inputs (x/ctx/adj) — coalesced vector bursts ----
    {
        const int lim = (nbatch - base) * 63;       // guard for partial tail
        if (t < 126 && t * 4 + 3 < lim)
            ((float4*)sh_x)[t] = ((const float4*)(x + base * 63))[t];
        const int lim45 = (nbatch - base) * 45;
        if (t < 90 && t * 4 + 3 < lim45) {
            ((float4*)sh_ctx)[t] = ((const float4*)(ctx + base * 45))[t];
            ((int4v*)sh_adj)[t]  = ((const int4v*)(adj + base * 45))[t];
        }
    }

    __syncthreads();   // ALL staging (W2 + inputs) complete before any read

    // ---- two wave-uniform batches per wave ----
    const int w  = t >> 6;
    const int bA = __builtin_amdgcn_readfirstlane(base + w);
    const int bBr = bA + 4;                                    // batch B raw
    const bool hasB = (bBr < nbatch);
    const int bB = __builtin_amdgcn_readfirstlane(hasB ? bBr : bA);
    const int wB = hasB ? (w + 4) : w;

    const int p = lane < 63 ? lane : 62;
    const int n = p / 7;
    const int f = p - n * 7;

    // ========== PHASE 1 (dual, interleaved chains — all inputs from LDS) ==
    int avA = 0, avB = 0;
    if (lane < 45) { avA = sh_adj[w * 45 + lane]; avB = sh_adj[wB * 45 + lane]; }
    const uint64_t amA = __ballot(avA != 0);
    const uint64_t amB = __ballot(avB != 0);

    float dA[9], dB[9];
#pragma unroll
    for (int i = 0; i < 9; ++i) {
        const int s = 9 * i - (i * (i - 1)) / 2;
        const uint64_t mk = (1ull << (8 - i)) - 1ull;
        dA[i] = __frsqrt_rn((float)(1 + __popcll((amA >> (s + 1)) & mk)));
        dB[i] = __frsqrt_rn((float)(1 + __popcll((amB >> (s + 1)) & mk)));
    }

    const float* xbA = sh_x + w * 63;
    const float* xbB = sh_x + wB * 63;
    float yA = 0.f, yB = 0.f;
#pragma unroll
    for (int k = 0; k < 7; ++k) {
        const float g = gcn_W[k * 7 + f];            // shared across pair
        yA = fmaf(xbA[n * 7 + k], g, yA);
        yB = fmaf(xbB[n * 7 + k], g, yB);
    }

    // z dot: 3 accumulators per batch, chains interleaved
    float zA0 = 0.f, zA1 = 0.f, zA2 = 0.f, zB0 = 0.f, zB1 = 0.f, zB2 = 0.f;
    const int snn = 9 * n - (n * (n - 1)) / 2 - n;
#pragma unroll
    for (int m = 0; m < 9; ++m) {
        const float ymA = __shfl(yA, m * 7 + f);
        const float ymB = __shfl(yB, m * 7 + f);
        int sh = snn + m;
        sh = sh < 0 ? 0 : sh;
        const bool up = (m > n);
        const float tA = ((m == n) || (up && ((amA >> sh) & 1ull))) ? dA[m] : 0.f;
        const float tB = ((m == n) || (up && ((amB >> sh) & 1ull))) ? dB[m] : 0.f;
        if (m < 3)      { zA0 = fmaf(tA, ymA, zA0); zB0 = fmaf(tB, ymB, zB0); }
        else if (m < 6) { zA1 = fmaf(tA, ymA, zA1); zB1 = fmaf(tB, ymB, zB1); }
        else            { zA2 = fmaf(tA, ymA, zA2); zB2 = fmaf(tB, ymB, zB2); }
    }
    const float gbf = gcn_b[f];
    const float zvA = fmaf(dA[n], (zA0 + zA1) + zA2, gbf);
    const float zvB = fmaf(dB[n], (zB0 + zB1) + zB2, gbf);

    // ctx dots: cb* from LDS (broadcast reads); ctx_W cols shared by pair
    const float* cbA = sh_ctx + w * 45;
    const float* cbB = sh_ctx + wB * 45;
    const float cb0 = ctx_b[p];
    float aA0 = cb0, aA1 = 0.f, aA2 = 0.f, aA3 = 0.f;
    float aB0 = cb0, aB1 = 0.f, aB2 = 0.f, aB3 = 0.f;
#pragma unroll
    for (int q = 0; q < 44; q += 4) {
        const float w0 = ctx_W[q * 63 + p];
        const float w1 = ctx_W[(q + 1) * 63 + p];
        const float w2 = ctx_W[(q + 2) * 63 + p];
        const float w3 = ctx_W[(q + 3) * 63 + p];
        aA0 = fmaf(cbA[q],     w0, aA0);  aB0 = fmaf(cbB[q],     w0, aB0);
        aA1 = fmaf(cbA[q + 1], w1, aA1);  aB1 = fmaf(cbB[q + 1], w1, aB1);
        aA2 = fmaf(cbA[q + 2], w2, aA2);  aB2 = fmaf(cbB[q + 2], w2, aB2);
        aA3 = fmaf(cbA[q + 3], w3, aA3);  aB3 = fmaf(cbB[q + 3], w3, aB3);
    }
    const float w44 = ctx_W[44 * 63 + p];
    aA0 = fmaf(cbA[44], w44, aA0);  aB0 = fmaf(cbB[44], w44, aB0);
    const float cvA = fmaxf((aA0 + aA1) + (aA2 + aA3), 0.f);
    const float cvB = fmaxf((aB0 + aB1) + (aB2 + aB3), 0.f);

    // ========== PHASE 2: MFMA (operand-swapped, f16, dual-batch) ==========
    const int cl   = lane & 15;       // position within i-tile (B-operand n)
    const int quad = lane >> 4;       // k-octet / C row group (channel)
    const int s0 = (quad ^ (cl & 7)) * 16;

    float2 wp0[8], wp1[8];
    float  bb0[8], bb1[8];
#pragma unroll
    for (int j = 0; j < 8; ++j) {
        const int o = quad * 8 + j;
        wp0[j] = *(const float2*)(W1 + 2 * o);
        bb0[j] = b1[o];
        wp1[j] = *(const float2*)(W1 + 2 * (o + 32));
        bb1[j] = b1[o + 32];
    }

    const float4 b2q0 = *(const float4*)(b2 + quad * 4);
    const float4 b2q1 = *(const float4*)(b2 + 16 + quad * 4);
    const float4 b2q2 = *(const float4*)(b2 + 32 + quad * 4);
    const float4 b2q3 = *(const float4*)(b2 + 48 + quad * 4);
    const float4 wa0 = *(const float4*)(W3 + quad * 4);
    const float4 wa1 = *(const float4*)(W3 + 16 + quad * 4);
    const float4 wa2 = *(const float4*)(W3 + 32 + quad * 4);
    const float4 wa3 = *(const float4*)(W3 + 48 + quad * 4);
    const float4 wb0 = *(const float4*)(W3 + 64 + quad * 4);
    const float4 wb1 = *(const float4*)(W3 + 80 + quad * 4);
    const float4 wb2 = *(const float4*)(W3 + 96 + quad * 4);
    const float4 wb3 = *(const float4*)(W3 + 112 + quad * 4);
    const float b30 = b3[0], b31 = b3[1];
    float* __restrict__ obA = out + bA * 126;
    float* __restrict__ obB = out + bB * 126;

    const char* sh2bB_ = (const char*)sh2b;

    // epilogue: relu + W3 dot on 16 channels, quad-reduce, store
    auto epilogue = [&](const f32x4& a0, const f32x4& a1,
                        const f32x4& a2, const f32x4& a3,
                        float* obp, int pp, bool valid) {
        float q0, q1, h;
        h = fmaxf(a0[0], 0.f); q0 = h * wa0.x;            q1 = h * wb0.x;
        h = fmaxf(a0[1], 0.f); q0 = fmaf(h, wa0.y, q0);   q1 = fmaf(h, wb0.y, q1);
        h = fmaxf(a0[2], 0.f); q0 = fmaf(h, wa0.z, q0);   q1 = fmaf(h, wb0.z, q1);
        h = fmaxf(a0[3], 0.f); q0 = fmaf(h, wa0.w, q0);   q1 = fmaf(h, wb0.w, q1);
        h = fmaxf(a1[0], 0.f); q0 = fmaf(h, wa1.x, q0);   q1 = fmaf(h, wb1.x, q1);
        h = fmaxf(a1[1], 0.f); q0 = fmaf(h, wa1.y, q0);   q1 = fmaf(h, wb1.y, q1);
        h = fmaxf(a1[2], 0.f); q0 = fmaf(h, wa1.z, q0);   q1 = fmaf(h, wb1.z, q1);
        h = fmaxf(a1[3], 0.f); q0 = fmaf(h, wa1.w, q0);   q1 = fmaf(h, wb1.w, q1);
        h = fmaxf(a2[0], 0.f); q0 = fmaf(h, wa2.x, q0);   q1 = fmaf(h, wb2.x, q1);
        h = fmaxf(a2[1], 0.f); q0 = fmaf(h, wa2.y, q0);   q1 = fmaf(h, wb2.y, q1);
        h = fmaxf(a2[2], 0.f); q0 = fmaf(h, wa2.z, q0);   q1 = fmaf(h, wb2.z, q1);
        h = fmaxf(a2[3], 0.f); q0 = fmaf(h, wa2.w, q0);   q1 = fmaf(h, wb2.w, q1);
        h = fmaxf(a3[0], 0.f); q0 = fmaf(h, wa3.x, q0);   q1 = fmaf(h, wb3.x, q1);
        h = fmaxf(a3[1], 0.f); q0 = fmaf(h, wa3.y, q0);   q1 = fmaf(h, wb3.y, q1);
        h = fmaxf(a3[2], 0.f); q0 = fmaf(h, wa3.z, q0);   q1 = fmaf(h, wb3.z, q1);
        h = fmaxf(a3[3], 0.f); q0 = fmaf(h, wa3.w, q0);   q1 = fmaf(h, wb3.w, q1);
        q0 += __shfl_xor(q0, 16); q0 += __shfl_xor(q0, 32);
        q1 += __shfl_xor(q1, 16); q1 += __shfl_xor(q1, 32);
        if (quad == 0 && pp < NPOS && valid) {
            obp[pp]        = q0 + b30;
            obp[NPOS + pp] = q1 + b31;
        }
    };

#pragma unroll 1
    for (int i = 0; i < 4; ++i) {
        const float zmA = __shfl(zvA, i * 16 + cl);
        const float cmA = __shfl(cvA, i * 16 + cl);
        const float zmB = __shfl(zvB, i * 16 + cl);
        const float cmB = __shfl(cvB, i * 16 + cl);

        // h1 fragments for both batches (interleaved independent chains)
        uint4v pA0, pA1, pB0, pB1;
#pragma unroll
        for (int jj = 0; jj < 4; ++jj) {
            const float2 u0 = wp0[2*jj],   u1 = wp0[2*jj+1];
            const float2 v0 = wp1[2*jj],   v1 = wp1[2*jj+1];
            const float  c0 = bb0[2*jj],   c1 = bb0[2*jj+1];
            const float  e0 = bb1[2*jj],   e1 = bb1[2*jj+1];

            float ha = fmaxf(fmaf(u0.x, zmA, fmaf(u0.y, cmA, c0)), 0.f);
            float hb = fmaxf(fmaf(u1.x, zmA, fmaf(u1.y, cmA, c1)), 0.f);
            pA0[jj] = pack_f16(ha, hb);
            ha = fmaxf(fmaf(v0.x, zmA, fmaf(v0.y, cmA, e0)), 0.f);
            hb = fmaxf(fmaf(v1.x, zmA, fmaf(v1.y, cmA, e1)), 0.f);
            pA1[jj] = pack_f16(ha, hb);

            ha = fmaxf(fmaf(u0.x, zmB, fmaf(u0.y, cmB, c0)), 0.f);
            hb = fmaxf(fmaf(u1.x, zmB, fmaf(u1.y, cmB, c1)), 0.f);
            pB0[jj] = pack_f16(ha, hb);
            ha = fmaxf(fmaf(v0.x, zmB, fmaf(v0.y, cmB, e0)), 0.f);
            hb = fmaxf(fmaf(v1.x, zmB, fmaf(v1.y, cmB, e1)), 0.f);
            pB1[jj] = pack_f16(ha, hb);
        }
        const f16x8 ahA0 = __builtin_bit_cast(f16x8, pA0);
        const f16x8 ahA1 = __builtin_bit_cast(f16x8, pA1);
        const f16x8 ahB0 = __builtin_bit_cast(f16x8, pB0);
        const f16x8 ahB1 = __builtin_bit_cast(f16x8, pB1);

        f32x4 accA0 = {b2q0.x, b2q0.y, b2q0.z, b2q0.w};
        f32x4 accA1 = {b2q1.x, b2q1.y, b2q1.z, b2q1.w};
        f32x4 accA2 = {b2q2.x, b2q2.y, b2q2.z, b2q2.w};
        f32x4 accA3 = {b2q3.x, b2q3.y, b2q3.z, b2q3.w};
        f32x4 accB0 = accA0, accB1 = accA1, accB2 = accA2, accB3 = accA3;

        // A-operand W2 LDS reads shared by BOTH batches: 2 ds_read_b128
        // feed 4 MFMAs per STEP (A/B interleaved = independent).
#define STEP(nt) {                                                                      \
        int bo = cl * 128 + s0;                                                         \
        asm volatile("" : "+v"(bo));                                                    \
        const int bo2 = (cl * 128) | (s0 ^ 64);                                         \
        const f16x8 wf0 = *(const f16x8*)(sh2bB_ + bo  + ((nt) * 2048));                \
        const f16x8 wf1 = *(const f16x8*)(sh2bB_ + bo2 + ((nt) * 2048));                \
        accA##nt = __builtin_amdgcn_mfma_f32_16x16x32_f16(wf0, ahA0, accA##nt, 0, 0, 0); \
        accB##nt = __builtin_amdgcn_mfma_f32_16x16x32_f16(wf0, ahB0, accB##nt, 0, 0, 0); \
        accA##nt = __builtin_amdgcn_mfma_f32_16x16x32_f16(wf1, ahA1, accA##nt, 0, 0, 0); \
        accB##nt = __builtin_amdgcn_mfma_f32_16x16x32_f16(wf1, ahB1, accB##nt, 0, 0, 0); }
        STEP(0) STEP(1) STEP(2) STEP(3)
#undef STEP

        const int pp = i * 16 + cl;
        epilogue(accA0, accA1, accA2, accA3, obA, pp, true);
        epilogue(accB0, accB1, accB2, accB3, obB, pp, hasB);
    }
}

extern "C" void kernel_launch(void* const* d_in, const int* in_sizes, int n_in,
                              void* d_out, int out_size, void* d_ws, size_t ws_size,
                              hipStream_t stream) {
    const float* x     = (const float*)d_in[0];
    const int*   adj   = (const int*)  d_in[1];
    const float* ctx   = (const float*)d_in[2];
    const float* gcn_W = (const float*)d_in[3];
    const float* gcn_b = (const float*)d_in[4];
    const float* ctx_W = (const float*)d_in[5];
    const float* ctx_b = (const float*)d_in[6];
    const float* W1    = (const float*)d_in[7];
    const float* b1    = (const float*)d_in[8];
    const float* W2    = (const float*)d_in[9];
    const float* b2    = (const float*)d_in[10];
    const float* W3    = (const float*)d_in[11];
    const float* b3    = (const float*)d_in[12];
    float* out = (float*)d_out;

    const int nbatch = in_sizes[1] / 45;            // B = 32768
    const int grid = (nbatch + BPB - 1) / BPB;      // 8 batches per block
    carnet_fused<<<grid, BLOCK_SIZE, 0, stream>>>(
        x, adj, ctx, gcn_W, gcn_b, ctx_W, ctx_b,
        W1, b1, W2, b2, W3, b3, out, nbatch);
}